// Round 6
// baseline (475.559 us; speedup 1.0000x reference)
//
#include <hip/hip_runtime.h>
#include <hip/hip_fp16.h>
#include <cstdint>
#include <cstddef>

// KNN regressor v15r — resubmission of v15 (round-5 bench was an infra
// failure: "container failed twice", no counters). Kernel audited: no OOB,
// no divergent barriers, LDS 61.7 KB, pad reads never consumed.
//
// v15: LDS-shared B-tile knn_main (GEMM-canonical structure).
//   v14 post-mortem: QT=64 with per-wave-private B in registers needs ~220
//   VGPRs -> compiler capped at 128 and spilled (WRITE_SIZE 8->22 MB).
//   Fix: share the B-tile across waves via LDS. Each of 4 waves owns 16
//   queries (afh 16 regs, acc 16 regs); per iter a 64-row x K128 tile
//   (16 KB) is staged global->reg->LDS double-buffered (T14 async split:
//   loads issued one iter ahead, ds_write just before the single per-iter
//   barrier -> no vmcnt(0) drain of in-flight loads). Per wave per iter:
//   16 ds_read_b128 + 16 MFMA. Reg demand ~75 -> no spill at any cap.
//   candL: 56 LDS slots/query; overflow [56,128) writes directly to candG
//   (P ~1e-7/cell); >128 -> flagF fallback. LDS 61.7 KB -> 2 blocks/CU,
//   grid 512 = one round.
// Pipeline: prep_all -> reduce_mx -> sample_T -> knn_main -> finalize.
//
// MFMA 16x16x32 f16 layouts (HW-verified, learn_hip m89/m91/m120):
//   A[m][k]: m=lane&15, k=(lane>>4)*8+j ; B[k][n]: n=lane&15, k=(lane>>4)*8+j
//   C[m][n]: n=lane&15, m=(lane>>4)*4+reg
// Xs swizzle: half-index (n_base)*128 + (nt*4+ks)*512 + L*8 holds the 8 halves
//   of row (n_base + nt*16 + (L&15)), k = ks*32+(L>>4)*8..+8.
//   => a 64-row tile is a contiguous 16 KB run; LDS buffer uses the same
//   layout, so staging is a linear copy and ds_reads are conflict-free.

constexpr int Q_  = 4096;
constexpr int N_  = 100000;
constexpr int D_  = 128;
constexpr int K_  = 32;

constexpr int QT    = 64;             // queries per block (wave owns 16)
constexpr int TN    = 64;             // points per iteration (B-tile rows)
constexpr int NCH   = 8;              // chunks == XCDs (ch = lb & 7)
constexpr int CHUNK = 12544;          // 49*256
constexpr int KITERS = CHUNK / TN;    // 196
constexpr int NPAD  = NCH * CHUNK;    // 100352
constexpr int CW    = 128;            // global per-(query,chunk) capacity
constexpr int CWL   = 56;             // LDS candidate slots per query
constexpr int QTS   = 16;             // sample_T queries per block
constexpr int SAMP_M      = 8192;
constexpr int SAMP_STRIDE = 12;
constexpr int SAMP_OFF    = 5;        // max n = 8191*12+5 = 98297 < N_
constexpr int SAMP_ITERS  = SAMP_M / 256;  // 32

constexpr int XS_B  = NPAD / 64;      // 1568 blocks: Xs + tsq + maxima
constexpr int SAM_B = SAMP_M / 64;    // 128 blocks: Xsam + tsqS
constexpr int PQ_B  = Q_ / 4;         // 1024 blocks: Qh/qsq/qrs + flagF zero
constexpr int MXN   = XS_B * 4;       // 6272 per-wave maxima

typedef __attribute__((ext_vector_type(8))) _Float16 half8;
typedef __attribute__((ext_vector_type(4))) float    floatx4;
typedef unsigned long long ull;

#define DEV __device__ __forceinline__
constexpr ull DEADC = ~0ull;

DEV ull pack_cand(float score, unsigned int n) {
    unsigned int s = __float_as_uint(score);
    s = (s & 0x80000000u) ? ~s : (s | 0x80000000u);   // monotone u32 key
    return ((ull)s << 32) | (ull)n;
}
DEV float unpack_score(ull k) {
    unsigned int s = (unsigned int)(k >> 32);
    s = (s & 0x80000000u) ? (s ^ 0x80000000u) : ~s;
    return __uint_as_float(s);
}
DEV ull u64min(ull a, ull b) { return a < b ? a : b; }
DEV float inf_f() { return __int_as_float(0x7f800000); }

DEV ull bitonic64(ull v, int L) {            // full sort, ascending
    #pragma unroll
    for (int k2 = 2; k2 <= 64; k2 <<= 1)
        #pragma unroll
        for (int j2 = k2 >> 1; j2 >= 1; j2 >>= 1) {
            ull o = __shfl_xor(v, j2);
            bool up = ((L & k2) == 0);
            bool lo = ((L & j2) == 0);
            ull mn = u64min(v, o), mx = v ^ o ^ mn;
            v = (lo == up) ? mn : mx;
        }
    return v;
}
DEV ull bimerge64(ull v, int L) {            // sort a bitonic seq, ascending
    #pragma unroll
    for (int j2 = 32; j2 >= 1; j2 >>= 1) {
        ull o = __shfl_xor(v, j2);
        ull mn = u64min(v, o), mx = v ^ o ^ mn;
        v = ((L & j2) == 0) ? mn : mx;
    }
    return v;
}

// ------------------------------------------------------------- prep_all -----
__global__ void prep_all(const float* __restrict__ X, const float* __restrict__ Qm,
                         __half* __restrict__ Xs, float* __restrict__ tsq,
                         float* __restrict__ mxArr, float* __restrict__ mxArrH,
                         __half* __restrict__ Xsam, float* __restrict__ tsqS,
                         __half* __restrict__ Qh,
                         float* __restrict__ qsq, float* __restrict__ qrs,
                         int* __restrict__ flagF)
{
    const int tid = threadIdx.x, L = tid & 63, wv = tid >> 6;
    const int bx = blockIdx.x;
    const int am = L & 15, aq = L >> 4;

    if (bx < XS_B) {
        int t16 = bx * 4 + wv;
        int r = t16 * 16 + am;
        float ssq = 0.f, xr2 = 0.f, xh2 = 0.f;
        #pragma unroll
        for (int ks = 0; ks < 4; ++ks) {
            int c = ks * 32 + aq * 8;
            float v0=0,v1=0,v2=0,v3=0,v4=0,v5=0,v6=0,v7=0;
            if (r < N_) {
                float4 a = *(const float4*)(X + (size_t)r * D_ + c);
                float4 b = *(const float4*)(X + (size_t)r * D_ + c + 4);
                v0=a.x; v1=a.y; v2=a.z; v3=a.w; v4=b.x; v5=b.y; v6=b.z; v7=b.w;
            }
            half8 h;
            h[0]=(_Float16)v0; h[1]=(_Float16)v1; h[2]=(_Float16)v2; h[3]=(_Float16)v3;
            h[4]=(_Float16)v4; h[5]=(_Float16)v5; h[6]=(_Float16)v6; h[7]=(_Float16)v7;
            float c0=(float)h[0], c1=(float)h[1], c2=(float)h[2], c3=(float)h[3];
            float c4=(float)h[4], c5=(float)h[5], c6=(float)h[6], c7=(float)h[7];
            float r0=v0-c0, r1=v1-c1, r2=v2-c2, r3=v3-c3;
            float r4=v4-c4, r5=v5-c5, r6=v6-c6, r7=v7-c7;
            ssq += v0*v0+v1*v1+v2*v2+v3*v3+v4*v4+v5*v5+v6*v6+v7*v7;
            xr2 += r0*r0+r1*r1+r2*r2+r3*r3+r4*r4+r5*r5+r6*r6+r7*r7;
            xh2 += c0*c0+c1*c1+c2*c2+c3*c3+c4*c4+c5*c5+c6*c6+c7*c7;
            *(half8*)(Xs + ((size_t)(t16 * 4 + ks)) * 512 + L * 8) = h;
        }
        ssq += __shfl_xor(ssq, 16); ssq += __shfl_xor(ssq, 32);   // rowwise
        xr2 += __shfl_xor(xr2, 16); xr2 += __shfl_xor(xr2, 32);
        xh2 += __shfl_xor(xh2, 16); xh2 += __shfl_xor(xh2, 32);
        if (aq == 0) tsq[r] = (r < N_) ? ssq : inf_f();
        float m = xr2;                                            // max of 16 rows
        m = fmaxf(m, __shfl_xor(m, 1)); m = fmaxf(m, __shfl_xor(m, 2));
        m = fmaxf(m, __shfl_xor(m, 4)); m = fmaxf(m, __shfl_xor(m, 8));
        float mh = xh2;
        mh = fmaxf(mh, __shfl_xor(mh, 1)); mh = fmaxf(mh, __shfl_xor(mh, 2));
        mh = fmaxf(mh, __shfl_xor(mh, 4)); mh = fmaxf(mh, __shfl_xor(mh, 8));
        if (L == 0) { mxArr[t16] = m; mxArrH[t16] = mh; }         // race-free slots
    } else if (bx < XS_B + SAM_B) {
        int t16 = (bx - XS_B) * 4 + wv;
        int j = t16 * 16 + am;
        int n = j * SAMP_STRIDE + SAMP_OFF;       // < N_
        float ssq = 0.f;
        #pragma unroll
        for (int ks = 0; ks < 4; ++ks) {
            int c = ks * 32 + aq * 8;
            float4 a = *(const float4*)(X + (size_t)n * D_ + c);
            float4 b = *(const float4*)(X + (size_t)n * D_ + c + 4);
            half8 h;
            h[0]=(_Float16)a.x; h[1]=(_Float16)a.y; h[2]=(_Float16)a.z; h[3]=(_Float16)a.w;
            h[4]=(_Float16)b.x; h[5]=(_Float16)b.y; h[6]=(_Float16)b.z; h[7]=(_Float16)b.w;
            ssq += a.x*a.x + a.y*a.y + a.z*a.z + a.w*a.w
                 + b.x*b.x + b.y*b.y + b.z*b.z + b.w*b.w;
            *(half8*)(Xsam + ((size_t)(t16 * 4 + ks)) * 512 + L * 8) = h;
        }
        ssq += __shfl_xor(ssq, 16); ssq += __shfl_xor(ssq, 32);
        if (aq == 0) tsqS[j] = ssq;
    } else {
        int r = (bx - XS_B - SAM_B) * 4 + wv;     // < Q_
        float2 x = *(const float2*)(Qm + (size_t)r * D_ + 2 * L);
        __half h0 = __float2half(x.x), h1 = __float2half(x.y);
        size_t o = (size_t)r * D_ + 2 * L;
        Qh[o] = h0; Qh[o + 1] = h1;
        float r0 = x.x - __half2float(h0), r1 = x.y - __half2float(h1);
        float s  = x.x * x.x + x.y * x.y;
        float sr = r0 * r0 + r1 * r1;
        s  += __shfl_xor(s, 32);  s += __shfl_xor(s, 16);  s += __shfl_xor(s, 8);
        s  += __shfl_xor(s, 4);   s += __shfl_xor(s, 2);   s += __shfl_xor(s, 1);
        sr += __shfl_xor(sr, 32); sr += __shfl_xor(sr, 16); sr += __shfl_xor(sr, 8);
        sr += __shfl_xor(sr, 4);  sr += __shfl_xor(sr, 2);  sr += __shfl_xor(sr, 1);
        if (L == 0) { qsq[r] = s; qrs[r] = sr; flagF[r] = 0; }
    }
}

// ------------------------------------------------------------ reduce_mx -----
// Global max ||xr||^2 and ||xh||^2 over the per-wave maxima (one tiny block).
__global__ void reduce_mx(const float* __restrict__ mxArr,
                          const float* __restrict__ mxArrH,
                          float* __restrict__ mxOut)
{
    __shared__ float sR[4], sH[4];
    const int tid = threadIdx.x, L = tid & 63, wv = tid >> 6;
    float a = 0.f, b = 0.f;
    #pragma unroll 1
    for (int i = tid; i < MXN; i += 256) {     // independent-load grid stride
        a = fmaxf(a, mxArr[i]);
        b = fmaxf(b, mxArrH[i]);
    }
    #pragma unroll
    for (int s = 32; s; s >>= 1) {
        a = fmaxf(a, __shfl_xor(a, s));
        b = fmaxf(b, __shfl_xor(b, s));
    }
    if (L == 0) { sR[wv] = a; sH[wv] = b; }
    __syncthreads();
    if (tid == 0) {
        mxOut[0] = fmaxf(fmaxf(sR[0], sR[1]), fmaxf(sR[2], sR[3]));
        mxOut[1] = fmaxf(fmaxf(sH[0], sH[1]), fmaxf(sH[2], sH[3]));
    }
}

// ---------------------------------------------------------- sample_T --------
// T_q = 16th smallest of per-lane-top2 approx scores over the 8192 sample.
__global__ __launch_bounds__(256, 2) void sample_T(
    const __half* __restrict__ Qh, const __half* __restrict__ Xsam,
    const float* __restrict__ tsqS, const float* __restrict__ qsq,
    const float* __restrict__ qrs, const float* __restrict__ mxOut,
    float* __restrict__ Teff, float* __restrict__ rawT, float* __restrict__ EwA)
{
    __shared__ float sT[QTS][130];
    const int tid = threadIdx.x, L = tid & 63, wv = tid >> 6;
    const int qbase = blockIdx.x * QTS;
    const int nwv = wv * 64;
    const int am = L & 15, aq = L >> 4;

    half8 afh[4];
    #pragma unroll
    for (int ks = 0; ks < 4; ++ks) {
        size_t o = (size_t)(qbase + am) * D_ + ks * 32 + aq * 8;
        afh[ks] = *(const half8*)(Qh + o);
    }

    float t2a[4], t2b[4];
    #pragma unroll
    for (int rg = 0; rg < 4; ++rg) { t2a[rg] = inf_f(); t2b[rg] = inf_f(); }

    const __half* bp = Xsam + (size_t)nwv * 128 + (size_t)L * 8;
    const float*  tp = tsqS + nwv + am;

    half8 bc[4], bn[4];
    #pragma unroll
    for (int nt = 0; nt < 4; ++nt)
        bc[nt] = *(const half8*)(bp + nt * 2048);

    #pragma unroll 1
    for (int it = 0; it < SAMP_ITERS; ++it) {
        float ts[4];
        #pragma unroll
        for (int nt = 0; nt < 4; ++nt) ts[nt] = tp[nt * 16];

        floatx4 acc[4] = {};
        #pragma unroll
        for (int ks = 0; ks < 4; ++ks) {
            const __half* pp = (ks < 3) ? (bp + (ks + 1) * 512) : (bp + 32768);
            #pragma unroll
            for (int nt = 0; nt < 4; ++nt)
                bn[nt] = *(const half8*)(pp + nt * 2048);
            #pragma unroll
            for (int nt = 0; nt < 4; ++nt)
                acc[nt] = __builtin_amdgcn_mfma_f32_16x16x32_f16(
                    afh[ks], bc[nt], acc[nt], 0, 0, 0);
            #pragma unroll
            for (int nt = 0; nt < 4; ++nt) bc[nt] = bn[nt];
        }
        #pragma unroll
        for (int rg = 0; rg < 4; ++rg) {
            float m1 = t2a[rg], m2 = t2b[rg];
            #pragma unroll
            for (int nt = 0; nt < 4; ++nt) {
                float v = ts[nt] - 2.f * acc[nt][rg];
                if (v < m2) { if (v < m1) { m2 = m1; m1 = v; } else m2 = v; }
            }
            t2a[rg] = m1; t2b[rg] = m2;
        }
        bp += 32768; tp += 256;
    }
    #pragma unroll
    for (int rg = 0; rg < 4; ++rg) {
        int q = aq * 4 + rg;
        sT[q][wv * 32 + am * 2 + 0] = t2a[rg];
        sT[q][wv * 32 + am * 2 + 1] = t2b[rg];
    }
    __syncthreads();

    const float mxr = mxOut[0], mxh = mxOut[1];

    #pragma unroll 1
    for (int j = 0; j < 4; ++j) {
        int q = wv * 4 + j;
        float a = sT[q][2 * L], b = sT[q][2 * L + 1];
        float g = 0.f;
        #pragma unroll 1
        for (int r = 0; r < 16; ++r) {
            float mn = fminf(a, b);
            mn = fminf(mn, __shfl_xor(mn, 32)); mn = fminf(mn, __shfl_xor(mn, 16));
            mn = fminf(mn, __shfl_xor(mn, 8));  mn = fminf(mn, __shfl_xor(mn, 4));
            mn = fminf(mn, __shfl_xor(mn, 2));  mn = fminf(mn, __shfl_xor(mn, 1));
            g = mn;
            ull ba = __ballot(a == g);
            if (ba) { if (L == __ffsll(ba) - 1) a = inf_f(); }
            else    { ull bb = __ballot(b == g); if (L == __ffsll(bb) - 1) b = inf_f(); }
        }
        if (L == 0) {
            int gq = qbase + q;
            // |2(q.x - qh.xh)| <= 2|q|maxXr + 2|qr|maxXh (+ fp32 accum slack)
            float e = 2.f * (sqrtf(qsq[gq]) * sqrtf(mxr)
                           + sqrtf(qrs[gq]) * sqrtf(mxh)) + 0.02f;
            rawT[gq] = g; EwA[gq] = e; Teff[gq] = g + e;
        }
    }
}

// ------------------------------------------------------------- main ---------
// LDS-shared B-tile: 4 waves x 16 queries each; per iter one 64-row x K128
// tile (16 KB) staged global->reg->LDS (double-buffered, 1 barrier/iter).
// Per wave per iter: 16 ds_read_b128 + 16 MFMA. ~75 VGPR -> no spills.
__global__ __launch_bounds__(256, 2) void knn_main(
    const __half* __restrict__ Qh, const __half* __restrict__ Xs,
    const float* __restrict__ tsq, const float* __restrict__ Teff,
    ull* __restrict__ candG, int* __restrict__ cntC, int* __restrict__ flagF)
{
    __shared__ __half bufA[2][TN * D_];           // 2 x 16 KB B-tile dbuf
    __shared__ ull candL[QT][CWL];                // 28.7 KB
    __shared__ int cntL[QT];

    const int tid = threadIdx.x, L = tid & 63, wv = tid >> 6;
    const int lb = blockIdx.x, ch = lb & 7;       // == XCD: one chunk per L2
    const int qbase = (lb >> 3) * QT, chBase = ch * CHUNK;
    const int am = L & 15, aq = L >> 4;

    if (tid < QT) cntL[tid] = 0;

    // wave's 16 queries: qbase + wv*16 + m, m = aq*4+rg (C-layout rows)
    float th[4];
    #pragma unroll
    for (int rg = 0; rg < 4; ++rg)
        th[rg] = Teff[qbase + wv * 16 + aq * 4 + rg];
    float maxTh = fmaxf(fmaxf(th[0], th[1]), fmaxf(th[2], th[3]));
    maxTh = fmaxf(maxTh, __shfl_xor(maxTh, 16));
    maxTh = fmaxf(maxTh, __shfl_xor(maxTh, 32));
    const float nH = -0.5f * maxTh - 1e-3f;       // strictly conservative

    half8 afh[4];
    #pragma unroll
    for (int ks = 0; ks < 4; ++ks) {
        size_t o = (size_t)(qbase + wv * 16 + am) * D_ + ks * 32 + aq * 8;
        afh[ks] = *(const half8*)(Qh + o);
    }

    // staging: tile it = contiguous 16 KB at Xs + (chBase + it*TN)*128 halves
    const __half* src = Xs + (size_t)chBase * D_ + tid * 8;
    const float*  tp  = tsq + chBase + am;

    half8 st[4];
    #pragma unroll
    for (int r = 0; r < 4; ++r)                   // tile 0 -> regs
        st[r] = *(const half8*)(src + r * 2048);
    #pragma unroll
    for (int r = 0; r < 4; ++r)                   // regs -> buf0
        *(half8*)(&bufA[0][r * 2048 + tid * 8]) = st[r];
    #pragma unroll
    for (int r = 0; r < 4; ++r)                   // tile 1 -> regs
        st[r] = *(const half8*)(src + 8192 + r * 2048);
    const __half* srcp = src + 16384;             // tile it+2 source
    __syncthreads();

    #pragma unroll 1
    for (int it = 0; it < KITERS; ++it) {
        const __half* bb = &bufA[it & 1][0];
        float ts[4];
        #pragma unroll
        for (int nt = 0; nt < 4; ++nt) ts[nt] = tp[it * TN + nt * 16];

        floatx4 acc[4] = {};
        #pragma unroll
        for (int ks = 0; ks < 4; ++ks)
            #pragma unroll
            for (int nt = 0; nt < 4; ++nt) {
                half8 b = *(const half8*)(bb + (nt * 4 + ks) * 512 + L * 8);
                acc[nt] = __builtin_amdgcn_mfma_f32_16x16x32_f16(
                    afh[ks], b, acc[nt], 0, 0, 0);
            }

        // conservative detection on raw dot; record hits
        unsigned hit = 0;
        #pragma unroll
        for (int nt = 0; nt < 4; ++nt) {
            float mx = fmaxf(fmaxf(acc[nt][0], acc[nt][1]),
                             fmaxf(acc[nt][2], acc[nt][3]));
            float Gm = fmaf(0.5f, ts[nt], nH);
            if (mx > Gm) hit |= 1u << nt;
        }
        if (__any(hit != 0)) {
            #pragma unroll
            for (int nt = 0; nt < 4; ++nt) {
                if (!__any(hit & (1u << nt))) continue;
                unsigned n = (unsigned)(chBase + it * TN + nt * 16 + am);
                #pragma unroll
                for (int rg = 0; rg < 4; ++rg) {
                    float s = fmaf(-2.f, acc[nt][rg], ts[nt]);
                    if (s < th[rg]) {
                        int q = wv * 16 + aq * 4 + rg;
                        int pos = atomicAdd(&cntL[q], 1);        // LDS atomic
                        if (pos < CWL)
                            candL[q][pos] = pack_cand(s, n);
                        else if (pos < CW)                       // rare: direct
                            candG[((size_t)(qbase + q) * NCH + ch) * CW + pos]
                                = pack_cand(s, n);
                        else
                            flagF[qbase + q] = 1;                // P ~ tiny
                    }
                }
            }
        }

        // write tile it+1 into the other buffer; issue loads for tile it+2
        {
            __half* wb = &bufA[(it + 1) & 1][0];
            #pragma unroll
            for (int r = 0; r < 4; ++r)
                *(half8*)(wb + r * 2048 + tid * 8) = st[r];
            #pragma unroll
            for (int r = 0; r < 4; ++r)
                st[r] = *(const half8*)(srcp + r * 2048);
            srcp += 8192;                         // last iters read Xs pad
        }
        __syncthreads();
    }

    // dump LDS candidates (overflow [CWL,CW) already in candG)
    #pragma unroll 1
    for (int j = 0; j < 16; ++j) {
        int q = wv * 16 + j;
        int gq = qbase + q;
        int c = cntL[q];
        int cc = c < CW ? c : CW;
        int ccl = c < CWL ? c : CWL;
        ull* dst = candG + ((size_t)gq * NCH + ch) * CW;
        if (L < ccl) dst[L] = candL[q][L];        // CWL <= 64: one pass
        if (L == 0) cntC[gq * NCH + ch] = cc;
    }
}

// ---------------------------------------- finalize (+ cheap fallback) -------
__global__ void finalize(const ull* __restrict__ candG, const int* __restrict__ cntC,
                         const int* __restrict__ flagF, const float* __restrict__ Qm,
                         const float* __restrict__ X, const float* __restrict__ tsq,
                         const float* __restrict__ rawT, const float* __restrict__ EwA,
                         const float* __restrict__ Ytr, float* __restrict__ out)
{
    __shared__ ull fb[4][256];                    // fallback collect buffers
    int L = threadIdx.x & 63;
    int wv = threadIdx.x >> 6;
    int q = blockIdx.x * 4 + wv;                  // one wave per query
    bool bad = (flagF[q] != 0);
    float result = 0.f;

    if (!bad) {
        int cg = (L < NCH) ? cntC[q * NCH + L] : 0;
        int ctot = cg;
        ctot += __shfl_xor(ctot, 32); ctot += __shfl_xor(ctot, 16);
        ctot += __shfl_xor(ctot, 8);  ctot += __shfl_xor(ctot, 4);
        ctot += __shfl_xor(ctot, 2);  ctot += __shfl_xor(ctot, 1);
        if (ctot < K_) bad = true;
        else {
            ull s = DEADC;
            #pragma unroll 1
            for (int g = 0; g < NCH; ++g) {
                int c_g = __shfl(cg, g);
                const ull* cb = candG + ((size_t)q * NCH + g) * CW;
                #pragma unroll 1
                for (int off = 0; off < c_g; off += 64) {
                    ull v = (off + L < c_g) ? cb[off + L] : DEADC;
                    v = bitonic64(v, L);
                    ull w = __shfl(v, 63 - L);
                    s = bimerge64(u64min(s, w), L);
                }
            }
            int cr = ctot < 64 ? ctot : 64;
            unsigned n = (unsigned)(s & 0xffffffffu);
            ull pe = DEADC;
            if (L < cr) {
                const float4* xp = (const float4*)(X + (size_t)n * D_);
                const float4* qp = (const float4*)(Qm + (size_t)q * D_);
                float d = 0.f;
                #pragma unroll 8
                for (int i = 0; i < 32; ++i) {
                    float4 xv = xp[i], qv = qp[i];
                    d += qv.x * xv.x + qv.y * xv.y + qv.z * xv.z + qv.w * xv.w;
                }
                pe = pack_cand(tsq[n] - 2.f * d, n);
            }
            ull pe2 = bitonic64(pe, L);
            float exact31 = unpack_score(__shfl(pe2, K_ - 1));
            bool ok = exact31 < rawT[q];
            if (ctot > 64) {
                float A63 = unpack_score(__shfl(s, 63));
                ok = ok && (A63 - EwA[q] > exact31);
            }
            if (!ok) bad = true;
            else {
                float ys = 0.f;
                if (L < K_) ys = Ytr[(unsigned)(pe2 & 0xffffffffu)];
                ys += __shfl_xor(ys, 32); ys += __shfl_xor(ys, 16);
                ys += __shfl_xor(ys, 8);  ys += __shfl_xor(ys, 4);
                ys += __shfl_xor(ys, 2);  ys += __shfl_xor(ys, 1);
                result = ys * (1.f / K_);
            }
        }
    }

    if (bad) {   // exact fallback: thresholded single-pass collect + bisection
        const float4* qp = (const float4*)(Qm + (size_t)q * D_);
        float T = rawT[q] + EwA[q];
        float lo = 0.f, hi = 0.f;
        bool haveLo = false, haveHi = false;
        int cnt = 0;
        #pragma unroll 1
        for (int att = 0; att < 40; ++att) {
            cnt = 0;
            #pragma unroll 1
            for (int j = 0; j < NPAD / 64; ++j) {
                int n = j * 64 + L;
                float s = inf_f();
                if (n < N_) {
                    const float4* xp = (const float4*)(X + (size_t)n * D_);
                    float d = 0.f;
                    #pragma unroll 4
                    for (int i = 0; i < 32; ++i) {
                        float4 xv = xp[i], qv = qp[i];
                        d += qv.x * xv.x + qv.y * xv.y + qv.z * xv.z + qv.w * xv.w;
                    }
                    s = tsq[n] - 2.f * d;
                }
                bool want = s < T;
                ull m = __ballot(want);
                if (m) {
                    int pos = cnt + (int)__popcll(m & ((1ull << L) - 1ull));
                    if (want && pos < 256) fb[wv][pos] = pack_cand(s, (unsigned)n);
                    cnt += (int)__popcll(m);
                }
            }
            if (cnt >= K_ && cnt <= 256) break;
            if (cnt < K_) { lo = T; haveLo = true;
                T = haveHi ? 0.5f * (T + hi) : T + exp2f((float)att) * 0.5f; }
            else { hi = T; haveHi = true;
                T = haveLo ? 0.5f * (lo + T) : T - exp2f((float)att) * 0.5f; }
        }
        if (cnt >= K_ && cnt <= 256) {
            ull s64 = DEADC;
            #pragma unroll 1
            for (int off = 0; off < 256; off += 64) {
                if (off >= cnt) break;
                ull v = (off + L < cnt) ? fb[wv][off + L] : DEADC;
                v = bitonic64(v, L);
                ull w = __shfl(v, 63 - L);
                s64 = bimerge64(u64min(s64, w), L);
            }
            float ys = (L < K_) ? Ytr[(unsigned)(s64 & 0xffffffffu)] : 0.f;
            ys += __shfl_xor(ys, 32); ys += __shfl_xor(ys, 16);
            ys += __shfl_xor(ys, 8);  ys += __shfl_xor(ys, 4);
            ys += __shfl_xor(ys, 2);  ys += __shfl_xor(ys, 1);
            result = ys * (1.f / K_);
        } else {   // last resort: 32-round exact tournament (never expected)
            ull last = 0;
            float ysum = 0.f;
            for (int r = 0; r < K_; ++r) {
                ull best = DEADC;
                for (int j = 0; j < NPAD / 64; ++j) {
                    int n = j * 64 + L;
                    if (n < N_) {
                        const float4* xp = (const float4*)(X + (size_t)n * D_);
                        float d = 0.f;
                        #pragma unroll 4
                        for (int i = 0; i < 32; ++i) {
                            float4 xv = xp[i], qv = qp[i];
                            d += qv.x * xv.x + qv.y * xv.y + qv.z * xv.z + qv.w * xv.w;
                        }
                        ull k = pack_cand(tsq[n] - 2.f * d, n);
                        if (k > last && k < best) best = k;
                    }
                }
                best = u64min(best, __shfl_xor(best, 32));
                best = u64min(best, __shfl_xor(best, 16));
                best = u64min(best, __shfl_xor(best, 8));
                best = u64min(best, __shfl_xor(best, 4));
                best = u64min(best, __shfl_xor(best, 2));
                best = u64min(best, __shfl_xor(best, 1));
                if (L == 0) ysum += Ytr[(unsigned)(best & 0xffffffffu)];
                last = best;
            }
            result = ysum * (1.f / K_);
        }
    }
    if (L == 0) out[q] = result;
}

// ------------------------------------------------------------- launch -------
extern "C" void kernel_launch(void* const* d_in, const int* in_sizes, int n_in,
                              void* d_out, int out_size, void* d_ws, size_t ws_size,
                              hipStream_t stream)
{
    const float* Qm  = (const float*)d_in[0];   // [4096,128]
    const float* X   = (const float*)d_in[1];   // [100000,128]
    const float* Ytr = (const float*)d_in[2];   // [100000]
    float* out = (float*)d_out;                 // [4096]

    char* w = (char*)d_ws;
    auto alloc = [&](size_t bytes) {
        char* p = w; w += (bytes + 255) & ~(size_t)255; return p;
    };
    __half* Xs   = (__half*)  alloc((size_t)(NPAD + 256) * D_ * 2);  // 25.8 MB (+prefetch pad)
    __half* Qh   = (__half*)  alloc((size_t)Q_ * D_ * 2);            // 1 MB
    float*  ts   = (float*)   alloc((size_t)NPAD * 4);               // 0.4 MB
    __half* Xsm  = (__half*)  alloc((size_t)(SAMP_M + 256) * D_ * 2);// 2.1 MB (+pad)
    float*  tsS  = (float*)   alloc((size_t)SAMP_M * 4);             // 32 KB
    ull*    cd   = (ull*)     alloc((size_t)Q_ * NCH * CW * 8);      // 33.6 MB
    int*    cnC  = (int*)     alloc((size_t)Q_ * NCH * 4);           // 128 KB
    int*    flg  = (int*)     alloc((size_t)Q_ * 4);                 // 16 KB
    float*  mxA  = (float*)   alloc((size_t)MXN * 4);                // 25 KB
    float*  mxAH = (float*)   alloc((size_t)MXN * 4);                // 25 KB
    float*  mxO  = (float*)   alloc(256);                            // 2 floats
    float*  Tef  = (float*)   alloc((size_t)Q_ * 4);
    float*  rwT  = (float*)   alloc((size_t)Q_ * 4);
    float*  Ew   = (float*)   alloc((size_t)Q_ * 4);
    float*  qs   = (float*)   alloc((size_t)Q_ * 4);
    float*  qr2  = (float*)   alloc((size_t)Q_ * 4);                 // total ~63 MB

    prep_all<<<XS_B + SAM_B + PQ_B, 256, 0, stream>>>(
        X, Qm, Xs, ts, mxA, mxAH, Xsm, tsS, Qh, qs, qr2, flg);
    reduce_mx<<<1, 256, 0, stream>>>(mxA, mxAH, mxO);
    sample_T<<<Q_ / QTS, 256, 0, stream>>>(Qh, Xsm, tsS, qs, qr2, mxO,
                                           Tef, rwT, Ew);
    knn_main<<<(Q_ / QT) * NCH, 256, 0, stream>>>(Qh, Xs, ts, Tef, cd, cnC, flg);
    finalize<<<Q_ / 4, 256, 0, stream>>>(cd, cnC, flg, Qm, X, ts, rwT, Ew, Ytr, out);
}

// Round 7
// 401.958 us; speedup vs baseline: 1.1831x; 1.1831x over previous
//
#include <hip/hip_runtime.h>
#include <hip/hip_fp16.h>
#include <cstdint>
#include <cstddef>

// KNN regressor v16 — v13 body + 16 sub-chunks (2048 blocks).
//   v15 post-mortem: barrier-per-16-MFMA lockstep regressed (281 us, Mfma
//   15.5%) -> private-register streaming (v13) stays. v13's limiter is
//   latency at low residency: 1024-block grids settle at ~1.7 blocks/CU
//   (occ 21%) while 2048-block grids reach ~3.2 (occ 39%, v10/v12).
//   Split each XCD chunk in half: 16 sub-chunks (ch = lb&7 keeps L2
//   locality, half = bit3), grid 2048. Per-block rows halve -> total L2
//   traffic unchanged (3.3 GB), resident waves ~2x. Candidates: 64 slots
//   per (query, sub-chunk) LDS (exp ~13, overflow -> exact flagF fallback).
// Pipeline: prep_all -> reduce_mx -> sample_T -> knn_main -> finalize.
//
// MFMA 16x16x32 f16 layouts (HW-verified, learn_hip m89/m91/m120):
//   A[m][k]: m=lane&15, k=(lane>>4)*8+j ; B[k][n]: n=lane&15, k=(lane>>4)*8+j
//   C[m][n]: n=lane&15, m=(lane>>4)*4+reg
// Xs swizzle: half-index (n_base)*128 + (nt*4+ks)*512 + L*8 holds the 8 halves
//   of row (n_base + nt*16 + (L&15)), k = ks*32+(L>>4)*8..+8.

constexpr int Q_  = 4096;
constexpr int N_  = 100000;
constexpr int D_  = 128;
constexpr int K_  = 32;

constexpr int QT    = 32;             // queries per block (two 16-row A tiles)
constexpr int BN    = 256;            // n per iteration
constexpr int NCH   = 8;              // XCD chunks (ch = lb & 7)
constexpr int NSUB  = 16;             // sub-chunks = grid replication factor
constexpr int CHUNK = 12544;          // 49*256 rows per XCD chunk
constexpr int HALF0 = 6400;           // 25*256 (first half of a chunk)
constexpr int NPAD  = NCH * CHUNK;    // 100352
constexpr int CWS   = 64;             // per-(query,sub-chunk) capacity
constexpr int QTS   = 16;             // sample_T queries per block
constexpr int SAMP_M      = 8192;
constexpr int SAMP_STRIDE = 12;
constexpr int SAMP_OFF    = 5;        // max n = 8191*12+5 = 98297 < N_
constexpr int SAMP_ITERS  = SAMP_M / BN;   // 32

constexpr int XS_B  = NPAD / 64;      // 1568 blocks: Xs + tsq + maxima
constexpr int SAM_B = SAMP_M / 64;    // 128 blocks: Xsam + tsqS
constexpr int PQ_B  = Q_ / 4;         // 1024 blocks: Qh/qsq/qrs + flagF zero
constexpr int MXN   = XS_B * 4;       // 6272 per-wave maxima

typedef __attribute__((ext_vector_type(8))) _Float16 half8;
typedef __attribute__((ext_vector_type(4))) float    floatx4;
typedef unsigned long long ull;

#define DEV __device__ __forceinline__
constexpr ull DEADC = ~0ull;

DEV ull pack_cand(float score, unsigned int n) {
    unsigned int s = __float_as_uint(score);
    s = (s & 0x80000000u) ? ~s : (s | 0x80000000u);   // monotone u32 key
    return ((ull)s << 32) | (ull)n;
}
DEV float unpack_score(ull k) {
    unsigned int s = (unsigned int)(k >> 32);
    s = (s & 0x80000000u) ? (s ^ 0x80000000u) : ~s;
    return __uint_as_float(s);
}
DEV ull u64min(ull a, ull b) { return a < b ? a : b; }
DEV float inf_f() { return __int_as_float(0x7f800000); }

DEV ull bitonic64(ull v, int L) {            // full sort, ascending
    #pragma unroll
    for (int k2 = 2; k2 <= 64; k2 <<= 1)
        #pragma unroll
        for (int j2 = k2 >> 1; j2 >= 1; j2 >>= 1) {
            ull o = __shfl_xor(v, j2);
            bool up = ((L & k2) == 0);
            bool lo = ((L & j2) == 0);
            ull mn = u64min(v, o), mx = v ^ o ^ mn;
            v = (lo == up) ? mn : mx;
        }
    return v;
}
DEV ull bimerge64(ull v, int L) {            // sort a bitonic seq, ascending
    #pragma unroll
    for (int j2 = 32; j2 >= 1; j2 >>= 1) {
        ull o = __shfl_xor(v, j2);
        ull mn = u64min(v, o), mx = v ^ o ^ mn;
        v = ((L & j2) == 0) ? mn : mx;
    }
    return v;
}

// ------------------------------------------------------------- prep_all -----
__global__ void prep_all(const float* __restrict__ X, const float* __restrict__ Qm,
                         __half* __restrict__ Xs, float* __restrict__ tsq,
                         float* __restrict__ mxArr, float* __restrict__ mxArrH,
                         __half* __restrict__ Xsam, float* __restrict__ tsqS,
                         __half* __restrict__ Qh,
                         float* __restrict__ qsq, float* __restrict__ qrs,
                         int* __restrict__ flagF)
{
    const int tid = threadIdx.x, L = tid & 63, wv = tid >> 6;
    const int bx = blockIdx.x;
    const int am = L & 15, aq = L >> 4;

    if (bx < XS_B) {
        int t16 = bx * 4 + wv;
        int r = t16 * 16 + am;
        float ssq = 0.f, xr2 = 0.f, xh2 = 0.f;
        #pragma unroll
        for (int ks = 0; ks < 4; ++ks) {
            int c = ks * 32 + aq * 8;
            float v0=0,v1=0,v2=0,v3=0,v4=0,v5=0,v6=0,v7=0;
            if (r < N_) {
                float4 a = *(const float4*)(X + (size_t)r * D_ + c);
                float4 b = *(const float4*)(X + (size_t)r * D_ + c + 4);
                v0=a.x; v1=a.y; v2=a.z; v3=a.w; v4=b.x; v5=b.y; v6=b.z; v7=b.w;
            }
            half8 h;
            h[0]=(_Float16)v0; h[1]=(_Float16)v1; h[2]=(_Float16)v2; h[3]=(_Float16)v3;
            h[4]=(_Float16)v4; h[5]=(_Float16)v5; h[6]=(_Float16)v6; h[7]=(_Float16)v7;
            float c0=(float)h[0], c1=(float)h[1], c2=(float)h[2], c3=(float)h[3];
            float c4=(float)h[4], c5=(float)h[5], c6=(float)h[6], c7=(float)h[7];
            float r0=v0-c0, r1=v1-c1, r2=v2-c2, r3=v3-c3;
            float r4=v4-c4, r5=v5-c5, r6=v6-c6, r7=v7-c7;
            ssq += v0*v0+v1*v1+v2*v2+v3*v3+v4*v4+v5*v5+v6*v6+v7*v7;
            xr2 += r0*r0+r1*r1+r2*r2+r3*r3+r4*r4+r5*r5+r6*r6+r7*r7;
            xh2 += c0*c0+c1*c1+c2*c2+c3*c3+c4*c4+c5*c5+c6*c6+c7*c7;
            *(half8*)(Xs + ((size_t)(t16 * 4 + ks)) * 512 + L * 8) = h;
        }
        ssq += __shfl_xor(ssq, 16); ssq += __shfl_xor(ssq, 32);   // rowwise
        xr2 += __shfl_xor(xr2, 16); xr2 += __shfl_xor(xr2, 32);
        xh2 += __shfl_xor(xh2, 16); xh2 += __shfl_xor(xh2, 32);
        if (aq == 0) tsq[r] = (r < N_) ? ssq : inf_f();
        float m = xr2;                                            // max of 16 rows
        m = fmaxf(m, __shfl_xor(m, 1)); m = fmaxf(m, __shfl_xor(m, 2));
        m = fmaxf(m, __shfl_xor(m, 4)); m = fmaxf(m, __shfl_xor(m, 8));
        float mh = xh2;
        mh = fmaxf(mh, __shfl_xor(mh, 1)); mh = fmaxf(mh, __shfl_xor(mh, 2));
        mh = fmaxf(mh, __shfl_xor(mh, 4)); mh = fmaxf(mh, __shfl_xor(mh, 8));
        if (L == 0) { mxArr[t16] = m; mxArrH[t16] = mh; }         // race-free slots
    } else if (bx < XS_B + SAM_B) {
        int t16 = (bx - XS_B) * 4 + wv;
        int j = t16 * 16 + am;
        int n = j * SAMP_STRIDE + SAMP_OFF;       // < N_
        float ssq = 0.f;
        #pragma unroll
        for (int ks = 0; ks < 4; ++ks) {
            int c = ks * 32 + aq * 8;
            float4 a = *(const float4*)(X + (size_t)n * D_ + c);
            float4 b = *(const float4*)(X + (size_t)n * D_ + c + 4);
            half8 h;
            h[0]=(_Float16)a.x; h[1]=(_Float16)a.y; h[2]=(_Float16)a.z; h[3]=(_Float16)a.w;
            h[4]=(_Float16)b.x; h[5]=(_Float16)b.y; h[6]=(_Float16)b.z; h[7]=(_Float16)b.w;
            ssq += a.x*a.x + a.y*a.y + a.z*a.z + a.w*a.w
                 + b.x*b.x + b.y*b.y + b.z*b.z + b.w*b.w;
            *(half8*)(Xsam + ((size_t)(t16 * 4 + ks)) * 512 + L * 8) = h;
        }
        ssq += __shfl_xor(ssq, 16); ssq += __shfl_xor(ssq, 32);
        if (aq == 0) tsqS[j] = ssq;
    } else {
        int r = (bx - XS_B - SAM_B) * 4 + wv;     // < Q_
        float2 x = *(const float2*)(Qm + (size_t)r * D_ + 2 * L);
        __half h0 = __float2half(x.x), h1 = __float2half(x.y);
        size_t o = (size_t)r * D_ + 2 * L;
        Qh[o] = h0; Qh[o + 1] = h1;
        float r0 = x.x - __half2float(h0), r1 = x.y - __half2float(h1);
        float s  = x.x * x.x + x.y * x.y;
        float sr = r0 * r0 + r1 * r1;
        s  += __shfl_xor(s, 32);  s += __shfl_xor(s, 16);  s += __shfl_xor(s, 8);
        s  += __shfl_xor(s, 4);   s += __shfl_xor(s, 2);   s += __shfl_xor(s, 1);
        sr += __shfl_xor(sr, 32); sr += __shfl_xor(sr, 16); sr += __shfl_xor(sr, 8);
        sr += __shfl_xor(sr, 4);  sr += __shfl_xor(sr, 2);  sr += __shfl_xor(sr, 1);
        if (L == 0) { qsq[r] = s; qrs[r] = sr; flagF[r] = 0; }
    }
}

// ------------------------------------------------------------ reduce_mx -----
// Global max ||xr||^2 and ||xh||^2 over the per-wave maxima (one tiny block).
__global__ void reduce_mx(const float* __restrict__ mxArr,
                          const float* __restrict__ mxArrH,
                          float* __restrict__ mxOut)
{
    __shared__ float sR[4], sH[4];
    const int tid = threadIdx.x, L = tid & 63, wv = tid >> 6;
    float a = 0.f, b = 0.f;
    #pragma unroll 1
    for (int i = tid; i < MXN; i += 256) {     // independent-load grid stride
        a = fmaxf(a, mxArr[i]);
        b = fmaxf(b, mxArrH[i]);
    }
    #pragma unroll
    for (int s = 32; s; s >>= 1) {
        a = fmaxf(a, __shfl_xor(a, s));
        b = fmaxf(b, __shfl_xor(b, s));
    }
    if (L == 0) { sR[wv] = a; sH[wv] = b; }
    __syncthreads();
    if (tid == 0) {
        mxOut[0] = fmaxf(fmaxf(sR[0], sR[1]), fmaxf(sR[2], sR[3]));
        mxOut[1] = fmaxf(fmaxf(sH[0], sH[1]), fmaxf(sH[2], sH[3]));
    }
}

// ---------------------------------------------------------- sample_T --------
// T_q = 16th smallest of per-lane-top2 approx scores over the 8192 sample.
__global__ __launch_bounds__(256, 2) void sample_T(
    const __half* __restrict__ Qh, const __half* __restrict__ Xsam,
    const float* __restrict__ tsqS, const float* __restrict__ qsq,
    const float* __restrict__ qrs, const float* __restrict__ mxOut,
    float* __restrict__ Teff, float* __restrict__ rawT, float* __restrict__ EwA)
{
    __shared__ float sT[QTS][130];
    const int tid = threadIdx.x, L = tid & 63, wv = tid >> 6;
    const int qbase = blockIdx.x * QTS;
    const int nwv = wv * 64;
    const int am = L & 15, aq = L >> 4;

    half8 afh[4];
    #pragma unroll
    for (int ks = 0; ks < 4; ++ks) {
        size_t o = (size_t)(qbase + am) * D_ + ks * 32 + aq * 8;
        afh[ks] = *(const half8*)(Qh + o);
    }

    float t2a[4], t2b[4];
    #pragma unroll
    for (int rg = 0; rg < 4; ++rg) { t2a[rg] = inf_f(); t2b[rg] = inf_f(); }

    const __half* bp = Xsam + (size_t)nwv * 128 + (size_t)L * 8;
    const float*  tp = tsqS + nwv + am;

    half8 bc[4], bn[4];
    #pragma unroll
    for (int nt = 0; nt < 4; ++nt)
        bc[nt] = *(const half8*)(bp + nt * 2048);

    #pragma unroll 1
    for (int it = 0; it < SAMP_ITERS; ++it) {
        float ts[4];
        #pragma unroll
        for (int nt = 0; nt < 4; ++nt) ts[nt] = tp[nt * 16];

        floatx4 acc[4] = {};
        #pragma unroll
        for (int ks = 0; ks < 4; ++ks) {
            const __half* pp = (ks < 3) ? (bp + (ks + 1) * 512) : (bp + 32768);
            #pragma unroll
            for (int nt = 0; nt < 4; ++nt)
                bn[nt] = *(const half8*)(pp + nt * 2048);
            #pragma unroll
            for (int nt = 0; nt < 4; ++nt)
                acc[nt] = __builtin_amdgcn_mfma_f32_16x16x32_f16(
                    afh[ks], bc[nt], acc[nt], 0, 0, 0);
            #pragma unroll
            for (int nt = 0; nt < 4; ++nt) bc[nt] = bn[nt];
        }
        #pragma unroll
        for (int rg = 0; rg < 4; ++rg) {
            float m1 = t2a[rg], m2 = t2b[rg];
            #pragma unroll
            for (int nt = 0; nt < 4; ++nt) {
                float v = ts[nt] - 2.f * acc[nt][rg];
                if (v < m2) { if (v < m1) { m2 = m1; m1 = v; } else m2 = v; }
            }
            t2a[rg] = m1; t2b[rg] = m2;
        }
        bp += 32768; tp += BN;
    }
    #pragma unroll
    for (int rg = 0; rg < 4; ++rg) {
        int q = aq * 4 + rg;
        sT[q][wv * 32 + am * 2 + 0] = t2a[rg];
        sT[q][wv * 32 + am * 2 + 1] = t2b[rg];
    }
    __syncthreads();

    const float mxr = mxOut[0], mxh = mxOut[1];

    #pragma unroll 1
    for (int j = 0; j < 4; ++j) {
        int q = wv * 4 + j;
        float a = sT[q][2 * L], b = sT[q][2 * L + 1];
        float g = 0.f;
        #pragma unroll 1
        for (int r = 0; r < 16; ++r) {
            float mn = fminf(a, b);
            mn = fminf(mn, __shfl_xor(mn, 32)); mn = fminf(mn, __shfl_xor(mn, 16));
            mn = fminf(mn, __shfl_xor(mn, 8));  mn = fminf(mn, __shfl_xor(mn, 4));
            mn = fminf(mn, __shfl_xor(mn, 2));  mn = fminf(mn, __shfl_xor(mn, 1));
            g = mn;
            ull ba = __ballot(a == g);
            if (ba) { if (L == __ffsll(ba) - 1) a = inf_f(); }
            else    { ull bb = __ballot(b == g); if (L == __ffsll(bb) - 1) b = inf_f(); }
        }
        if (L == 0) {
            int gq = qbase + q;
            // |2(q.x - qh.xh)| <= 2|q|maxXr + 2|qr|maxXh (+ fp32 accum slack)
            float e = 2.f * (sqrtf(qsq[gq]) * sqrtf(mxr)
                           + sqrtf(qrs[gq]) * sqrtf(mxh)) + 0.02f;
            rawT[gq] = g; EwA[gq] = e; Teff[gq] = g + e;
        }
    }
}

// ------------------------------------------------------------- main ---------
// v13 body; sub-chunked. lb bits: [2:0]=ch (XCD), [3]=half, [>=4]=q-tile.
// 2-phase double-buffered K-loop, private-register B, no barriers in loop.
__global__ __launch_bounds__(256, 2) void knn_main(
    const __half* __restrict__ Qh, const __half* __restrict__ Xs,
    const float* __restrict__ tsq, const float* __restrict__ Teff,
    ull* __restrict__ candG, int* __restrict__ cntC, int* __restrict__ flagF)
{
    __shared__ ull candL[QT][CWS];                // 16 KB
    __shared__ int cntL[QT];

    const int tid = threadIdx.x, L = tid & 63, wv = tid >> 6;
    const int lb = blockIdx.x, ch = lb & 7;       // == XCD: one chunk per L2
    const int half = (lb >> 3) & 1, sub = lb & 15;
    const int qbase = (lb >> 4) * QT, nwv = wv * 64;
    const int rowBase = ch * CHUNK + half * HALF0;
    const int iters = half ? 24 : 25;             // 24*256 + 25*256 = CHUNK
    const int am = L & 15, aq = L >> 4;

    if (tid < QT) cntL[tid] = 0;
    __syncthreads();                              // barrier #1

    float th[2][4];
    float nH[2];
    #pragma unroll
    for (int qt = 0; qt < 2; ++qt) {
        #pragma unroll
        for (int rg = 0; rg < 4; ++rg)
            th[qt][rg] = Teff[qbase + qt * 16 + aq * 4 + rg];
        float m = fmaxf(fmaxf(th[qt][0], th[qt][1]), fmaxf(th[qt][2], th[qt][3]));
        nH[qt] = -0.5f * m - 1e-3f;               // strictly conservative
    }

    half8 afh[2][4];
    #pragma unroll
    for (int qt = 0; qt < 2; ++qt)
        #pragma unroll
        for (int ks = 0; ks < 4; ++ks) {
            size_t o = (size_t)(qbase + qt * 16 + am) * D_ + ks * 32 + aq * 8;
            afh[qt][ks] = *(const half8*)(Qh + o);
        }

    // pointer-increment addressing (32-bit strides, no per-load 64-bit chains)
    const __half* bp = Xs + (size_t)(rowBase + nwv) * 128 + (size_t)L * 8;
    const float*  tp = tsq + rowBase + nwv + am;
    int n0 = rowBase + nwv + am;

    // bx/by: 8 x half8 double-buffers. slot j = ks_sub*4 + nt, ks_sub in {0,1}.
    half8 bx[8], by[8];
    #pragma unroll
    for (int j = 0; j < 8; ++j)                    // prologue: (it0, k0..63)
        bx[j] = *(const half8*)(bp + (j >> 2) * 512 + (j & 3) * 2048);

    #pragma unroll 1
    for (int it = 0; it < iters; ++it) {
        float ts[4];
        #pragma unroll
        for (int nt = 0; nt < 4; ++nt) ts[nt] = tp[nt * 16];

        floatx4 acc[2][4] = {};

        // P0: issue (it, k64..127) -> by ; compute bx = (it, k0..63)
        #pragma unroll
        for (int j = 0; j < 8; ++j)
            by[j] = *(const half8*)(bp + (2 + (j >> 2)) * 512 + (j & 3) * 2048);
        #pragma unroll
        for (int ks = 0; ks < 2; ++ks)
            #pragma unroll
            for (int nt = 0; nt < 4; ++nt) {
                acc[0][nt] = __builtin_amdgcn_mfma_f32_16x16x32_f16(
                    afh[0][ks], bx[ks * 4 + nt], acc[0][nt], 0, 0, 0);
                acc[1][nt] = __builtin_amdgcn_mfma_f32_16x16x32_f16(
                    afh[1][ks], bx[ks * 4 + nt], acc[1][nt], 0, 0, 0);
            }

        // P1: issue (it+1, k0..63) -> bx ; compute by = (it, k64..127)
        //     (final prefetch reads the next sub-chunk / the Xs pad: valid mem)
        #pragma unroll
        for (int j = 0; j < 8; ++j)
            bx[j] = *(const half8*)(bp + 32768 + (j >> 2) * 512 + (j & 3) * 2048);
        #pragma unroll
        for (int ks = 0; ks < 2; ++ks)
            #pragma unroll
            for (int nt = 0; nt < 4; ++nt) {
                acc[0][nt] = __builtin_amdgcn_mfma_f32_16x16x32_f16(
                    afh[0][2 + ks], by[ks * 4 + nt], acc[0][nt], 0, 0, 0);
                acc[1][nt] = __builtin_amdgcn_mfma_f32_16x16x32_f16(
                    afh[1][2 + ks], by[ks * 4 + nt], acc[1][nt], 0, 0, 0);
            }

        // cheap conservative detection on raw dot:
        //   score < th  <=>  dot > (ts - th)/2 ; group bound uses maxTh+slack
        unsigned hit = 0;
        #pragma unroll
        for (int nt = 0; nt < 4; ++nt) {
            #pragma unroll
            for (int qt = 0; qt < 2; ++qt) {
                float mx = fmaxf(fmaxf(acc[qt][nt][0], acc[qt][nt][1]),
                                 fmaxf(acc[qt][nt][2], acc[qt][nt][3]));
                float Gm = fmaf(0.5f, ts[nt], nH[qt]);
                if (mx > Gm) hit |= 1u << (nt * 2 + qt);
            }
        }
        if (__any(hit != 0)) {
            #pragma unroll
            for (int nt = 0; nt < 4; ++nt) {
                #pragma unroll
                for (int qt = 0; qt < 2; ++qt) {
                    if (!__any(hit & (1u << (nt * 2 + qt)))) continue;
                    unsigned n = (unsigned)(n0 + nt * 16);
                    #pragma unroll
                    for (int rg = 0; rg < 4; ++rg) {
                        float s = fmaf(-2.f, acc[qt][nt][rg], ts[nt]);
                        if (s < th[qt][rg]) {
                            int q = qt * 16 + aq * 4 + rg;
                            int pos = atomicAdd(&cntL[q], 1);     // LDS atomic
                            if (pos < CWS)
                                candL[q][pos] = pack_cand(s, n);
                            else
                                flagF[qbase + q] = 1;             // exact fallback
                        }
                    }
                }
            }
        }
        bp += 32768; tp += BN; n0 += BN;
    }

    __syncthreads();                              // barrier #2 (pre-dump)

    #pragma unroll 1
    for (int j = 0; j < 8; ++j) {
        int q = wv * 8 + j;
        int gq = qbase + q;
        int c = cntL[q];
        int cc = c < CWS ? c : CWS;
        ull* dst = candG + ((size_t)gq * NSUB + sub) * CWS;
        if (L < cc) dst[L] = candL[q][L];         // CWS = 64: one pass
        if (L == 0) cntC[gq * NSUB + sub] = cc;
    }
}

// ---------------------------------------- finalize (+ cheap fallback) -------
__global__ void finalize(const ull* __restrict__ candG, const int* __restrict__ cntC,
                         const int* __restrict__ flagF, const float* __restrict__ Qm,
                         const float* __restrict__ X, const float* __restrict__ tsq,
                         const float* __restrict__ rawT, const float* __restrict__ EwA,
                         const float* __restrict__ Ytr, float* __restrict__ out)
{
    __shared__ ull fb[4][256];                    // fallback collect buffers
    int L = threadIdx.x & 63;
    int wv = threadIdx.x >> 6;
    int q = blockIdx.x * 4 + wv;                  // one wave per query
    bool bad = (flagF[q] != 0);
    float result = 0.f;

    if (!bad) {
        int cg = (L < NSUB) ? cntC[q * NSUB + L] : 0;
        int ctot = cg;
        ctot += __shfl_xor(ctot, 32); ctot += __shfl_xor(ctot, 16);
        ctot += __shfl_xor(ctot, 8);  ctot += __shfl_xor(ctot, 4);
        ctot += __shfl_xor(ctot, 2);  ctot += __shfl_xor(ctot, 1);
        if (ctot < K_) bad = true;
        else {
            ull s = DEADC;
            #pragma unroll 1
            for (int g = 0; g < NSUB; ++g) {
                int c_g = __shfl(cg, g);
                if (c_g == 0) continue;
                const ull* cb = candG + ((size_t)q * NSUB + g) * CWS;
                ull v = (L < c_g) ? cb[L] : DEADC;    // c_g <= 64
                v = bitonic64(v, L);
                ull w = __shfl(v, 63 - L);
                s = bimerge64(u64min(s, w), L);
            }
            int cr = ctot < 64 ? ctot : 64;
            unsigned n = (unsigned)(s & 0xffffffffu);
            ull pe = DEADC;
            if (L < cr) {
                const float4* xp = (const float4*)(X + (size_t)n * D_);
                const float4* qp = (const float4*)(Qm + (size_t)q * D_);
                float d = 0.f;
                #pragma unroll 8
                for (int i = 0; i < 32; ++i) {
                    float4 xv = xp[i], qv = qp[i];
                    d += qv.x * xv.x + qv.y * xv.y + qv.z * xv.z + qv.w * xv.w;
                }
                pe = pack_cand(tsq[n] - 2.f * d, n);
            }
            ull pe2 = bitonic64(pe, L);
            float exact31 = unpack_score(__shfl(pe2, K_ - 1));
            bool ok = exact31 < rawT[q];
            if (ctot > 64) {
                float A63 = unpack_score(__shfl(s, 63));
                ok = ok && (A63 - EwA[q] > exact31);
            }
            if (!ok) bad = true;
            else {
                float ys = 0.f;
                if (L < K_) ys = Ytr[(unsigned)(pe2 & 0xffffffffu)];
                ys += __shfl_xor(ys, 32); ys += __shfl_xor(ys, 16);
                ys += __shfl_xor(ys, 8);  ys += __shfl_xor(ys, 4);
                ys += __shfl_xor(ys, 2);  ys += __shfl_xor(ys, 1);
                result = ys * (1.f / K_);
            }
        }
    }

    if (bad) {   // exact fallback: thresholded single-pass collect + bisection
        const float4* qp = (const float4*)(Qm + (size_t)q * D_);
        float T = rawT[q] + EwA[q];
        float lo = 0.f, hi = 0.f;
        bool haveLo = false, haveHi = false;
        int cnt = 0;
        #pragma unroll 1
        for (int att = 0; att < 40; ++att) {
            cnt = 0;
            #pragma unroll 1
            for (int j = 0; j < NPAD / 64; ++j) {
                int n = j * 64 + L;
                float s = inf_f();
                if (n < N_) {
                    const float4* xp = (const float4*)(X + (size_t)n * D_);
                    float d = 0.f;
                    #pragma unroll 4
                    for (int i = 0; i < 32; ++i) {
                        float4 xv = xp[i], qv = qp[i];
                        d += qv.x * xv.x + qv.y * xv.y + qv.z * xv.z + qv.w * xv.w;
                    }
                    s = tsq[n] - 2.f * d;
                }
                bool want = s < T;
                ull m = __ballot(want);
                if (m) {
                    int pos = cnt + (int)__popcll(m & ((1ull << L) - 1ull));
                    if (want && pos < 256) fb[wv][pos] = pack_cand(s, (unsigned)n);
                    cnt += (int)__popcll(m);
                }
            }
            if (cnt >= K_ && cnt <= 256) break;
            if (cnt < K_) { lo = T; haveLo = true;
                T = haveHi ? 0.5f * (T + hi) : T + exp2f((float)att) * 0.5f; }
            else { hi = T; haveHi = true;
                T = haveLo ? 0.5f * (lo + T) : T - exp2f((float)att) * 0.5f; }
        }
        if (cnt >= K_ && cnt <= 256) {
            ull s64 = DEADC;
            #pragma unroll 1
            for (int off = 0; off < 256; off += 64) {
                if (off >= cnt) break;
                ull v = (off + L < cnt) ? fb[wv][off + L] : DEADC;
                v = bitonic64(v, L);
                ull w = __shfl(v, 63 - L);
                s64 = bimerge64(u64min(s64, w), L);
            }
            float ys = (L < K_) ? Ytr[(unsigned)(s64 & 0xffffffffu)] : 0.f;
            ys += __shfl_xor(ys, 32); ys += __shfl_xor(ys, 16);
            ys += __shfl_xor(ys, 8);  ys += __shfl_xor(ys, 4);
            ys += __shfl_xor(ys, 2);  ys += __shfl_xor(ys, 1);
            result = ys * (1.f / K_);
        } else {   // last resort: 32-round exact tournament (never expected)
            ull last = 0;
            float ysum = 0.f;
            for (int r = 0; r < K_; ++r) {
                ull best = DEADC;
                for (int j = 0; j < NPAD / 64; ++j) {
                    int n = j * 64 + L;
                    if (n < N_) {
                        const float4* xp = (const float4*)(X + (size_t)n * D_);
                        float d = 0.f;
                        #pragma unroll 4
                        for (int i = 0; i < 32; ++i) {
                            float4 xv = xp[i], qv = qp[i];
                            d += qv.x * xv.x + qv.y * xv.y + qv.z * xv.z + qv.w * xv.w;
                        }
                        ull k = pack_cand(tsq[n] - 2.f * d, n);
                        if (k > last && k < best) best = k;
                    }
                }
                best = u64min(best, __shfl_xor(best, 32));
                best = u64min(best, __shfl_xor(best, 16));
                best = u64min(best, __shfl_xor(best, 8));
                best = u64min(best, __shfl_xor(best, 4));
                best = u64min(best, __shfl_xor(best, 2));
                best = u64min(best, __shfl_xor(best, 1));
                if (L == 0) ysum += Ytr[(unsigned)(best & 0xffffffffu)];
                last = best;
            }
            result = ysum * (1.f / K_);
        }
    }
    if (L == 0) out[q] = result;
}

// ------------------------------------------------------------- launch -------
extern "C" void kernel_launch(void* const* d_in, const int* in_sizes, int n_in,
                              void* d_out, int out_size, void* d_ws, size_t ws_size,
                              hipStream_t stream)
{
    const float* Qm  = (const float*)d_in[0];   // [4096,128]
    const float* X   = (const float*)d_in[1];   // [100000,128]
    const float* Ytr = (const float*)d_in[2];   // [100000]
    float* out = (float*)d_out;                 // [4096]

    char* w = (char*)d_ws;
    auto alloc = [&](size_t bytes) {
        char* p = w; w += (bytes + 255) & ~(size_t)255; return p;
    };
    __half* Xs   = (__half*)  alloc((size_t)(NPAD + BN) * D_ * 2);   // 25.8 MB (+prefetch pad)
    __half* Qh   = (__half*)  alloc((size_t)Q_ * D_ * 2);            // 1 MB
    float*  ts   = (float*)   alloc((size_t)NPAD * 4);               // 0.4 MB
    __half* Xsm  = (__half*)  alloc((size_t)(SAMP_M + BN) * D_ * 2); // 2.1 MB (+pad)
    float*  tsS  = (float*)   alloc((size_t)SAMP_M * 4);             // 32 KB
    ull*    cd   = (ull*)     alloc((size_t)Q_ * NSUB * CWS * 8);    // 33.6 MB
    int*    cnC  = (int*)     alloc((size_t)Q_ * NSUB * 4);          // 256 KB
    int*    flg  = (int*)     alloc((size_t)Q_ * 4);                 // 16 KB
    float*  mxA  = (float*)   alloc((size_t)MXN * 4);                // 25 KB
    float*  mxAH = (float*)   alloc((size_t)MXN * 4);                // 25 KB
    float*  mxO  = (float*)   alloc(256);                            // 2 floats
    float*  Tef  = (float*)   alloc((size_t)Q_ * 4);
    float*  rwT  = (float*)   alloc((size_t)Q_ * 4);
    float*  Ew   = (float*)   alloc((size_t)Q_ * 4);
    float*  qs   = (float*)   alloc((size_t)Q_ * 4);
    float*  qr2  = (float*)   alloc((size_t)Q_ * 4);                 // total ~63 MB

    prep_all<<<XS_B + SAM_B + PQ_B, 256, 0, stream>>>(
        X, Qm, Xs, ts, mxA, mxAH, Xsm, tsS, Qh, qs, qr2, flg);
    reduce_mx<<<1, 256, 0, stream>>>(mxA, mxAH, mxO);
    sample_T<<<Q_ / QTS, 256, 0, stream>>>(Qh, Xsm, tsS, qs, qr2, mxO,
                                           Tef, rwT, Ew);
    knn_main<<<(Q_ / QT) * NSUB, 256, 0, stream>>>(Qh, Xs, ts, Tef, cd, cnC, flg);
    finalize<<<Q_ / 4, 256, 0, stream>>>(cd, cnC, flg, Qm, X, ts, rwT, Ew, Ytr, out);
}